// Round 1
// baseline (482.791 us; speedup 1.0000x reference)
//
#include <hip/hip_runtime.h>
#include <math.h>

#define B_  4096
#define F_  512
#define T_  2048
#define D_  4
#define TAU 0.2018004745467103f

// ---------------------------------------------------------------------------
// Kernel 1: row softmax over F for all T*D rows of feature_logits.
// feature_logits is (T, D, F) row-major == (T*D, F) row-major; softmax is
// over the last axis, so layout is preserved. One wave (64 lanes) per row,
// 8 elements/lane via two float4 loads. 4 rows per 256-thread block.
// ---------------------------------------------------------------------------
__global__ __launch_bounds__(256) void softmax_rows(
    const float* __restrict__ logits, float* __restrict__ w) {
  int row  = blockIdx.x * 4 + (threadIdx.x >> 6);
  int lane = threadIdx.x & 63;
  const float* src = logits + (size_t)row * F_;
  float4 v0 = *(const float4*)(src + lane * 4);
  float4 v1 = *(const float4*)(src + 256 + lane * 4);

  float mx = fmaxf(fmaxf(fmaxf(v0.x, v0.y), fmaxf(v0.z, v0.w)),
                   fmaxf(fmaxf(v1.x, v1.y), fmaxf(v1.z, v1.w)));
  #pragma unroll
  for (int m = 32; m >= 1; m >>= 1) mx = fmaxf(mx, __shfl_xor(mx, m, 64));

  float4 e0, e1;
  e0.x = __expf(v0.x - mx); e0.y = __expf(v0.y - mx);
  e0.z = __expf(v0.z - mx); e0.w = __expf(v0.w - mx);
  e1.x = __expf(v1.x - mx); e1.y = __expf(v1.y - mx);
  e1.z = __expf(v1.z - mx); e1.w = __expf(v1.w - mx);

  float s = e0.x + e0.y + e0.z + e0.w + e1.x + e1.y + e1.z + e1.w;
  #pragma unroll
  for (int m = 32; m >= 1; m >>= 1) s += __shfl_xor(s, m, 64);
  float inv = 1.0f / s;

  e0.x *= inv; e0.y *= inv; e0.z *= inv; e0.w *= inv;
  e1.x *= inv; e1.y *= inv; e1.z *= inv; e1.w *= inv;
  float* dst = w + (size_t)row * F_;
  *(float4*)(dst + lane * 4)       = e0;
  *(float4*)(dst + 256 + lane * 4) = e1;
}

// ---------------------------------------------------------------------------
// Kernel 2: fused GEMM (x[B,F] @ w[T*D,F]^T -> x_sel[B,T,D]) + sigmoid/leaf
// epilogue -> out[B,T].
// Block tile: 128 b  x 32 t (=128 n).  BK=32.  256 threads, 8x8 per thread.
// Thread (tx,ty): b = b0 + ty*8 + i (i<8);  t = t0 + tx + 16*jj (jj<2),
// n = t_local*4 + d  -> acc[i][jj*4+d] = x_sel(b, t, d).
// ---------------------------------------------------------------------------
#define BM 128
#define BN 128
#define BT 32
#define BK 32

__global__ __launch_bounds__(256) void odst_fused(
    const float* __restrict__ x, const float* __restrict__ w,
    const float* __restrict__ thr, const float* __restrict__ leaf,
    float* __restrict__ out) {
  // transposed LDS tiles [k][row], +4 pad keeps rows 16B-aligned and spreads banks
  __shared__ float xs[BK][BM + 4];
  __shared__ float ws[BK][BN + 4];

  const int tid = threadIdx.x;
  const int tx = tid & 15, ty = tid >> 4;
  const int b0 = blockIdx.y * BM;
  const int t0 = blockIdx.x * BT;
  const int n0 = t0 * 4;

  float acc[8][8];
  #pragma unroll
  for (int i = 0; i < 8; i++)
    #pragma unroll
    for (int j = 0; j < 8; j++) acc[i][j] = 0.0f;

  for (int k0 = 0; k0 < F_; k0 += BK) {
    __syncthreads();
    // stage: 128 rows x 32 k each for x and w; 4 float4 per thread per matrix
    #pragma unroll
    for (int q = 0; q < 4; q++) {
      int L = tid + q * 256;
      int row = L >> 3;
      int c4 = (L & 7) * 4;
      float4 v = *(const float4*)(x + (size_t)(b0 + row) * F_ + k0 + c4);
      xs[c4 + 0][row] = v.x; xs[c4 + 1][row] = v.y;
      xs[c4 + 2][row] = v.z; xs[c4 + 3][row] = v.w;
      float4 u = *(const float4*)(w + (size_t)(n0 + row) * F_ + k0 + c4);
      ws[c4 + 0][row] = u.x; ws[c4 + 1][row] = u.y;
      ws[c4 + 2][row] = u.z; ws[c4 + 3][row] = u.w;
    }
    __syncthreads();

    #pragma unroll
    for (int k = 0; k < BK; k++) {
      float4 a0 = *(const float4*)&xs[k][ty * 8];
      float4 a1 = *(const float4*)&xs[k][ty * 8 + 4];
      float4 q0 = *(const float4*)&ws[k][tx * 4];        // t_local = tx,    d=0..3
      float4 q1 = *(const float4*)&ws[k][tx * 4 + 64];   // t_local = 16+tx, d=0..3
      float a[8] = {a0.x, a0.y, a0.z, a0.w, a1.x, a1.y, a1.z, a1.w};
      float bb[8] = {q0.x, q0.y, q0.z, q0.w, q1.x, q1.y, q1.z, q1.w};
      #pragma unroll
      for (int i = 0; i < 8; i++)
        #pragma unroll
        for (int j = 0; j < 8; j++) acc[i][j] = fmaf(a[i], bb[j], acc[i][j]);
    }
  }

  // epilogue: p = sigmoid((x_sel - thr)/tau); out = sum_j leaf[j]*prod_d(bit?p:1-p)
  const float inv_tau = 1.0f / TAU;
  #pragma unroll
  for (int jj = 0; jj < 2; jj++) {
    int t = t0 + tx + 16 * jj;
    float th[4];
    #pragma unroll
    for (int d = 0; d < 4; d++) th[d] = thr[t * 4 + d];
    float lf[16];
    #pragma unroll
    for (int j = 0; j < 16; j++) lf[j] = leaf[t * 16 + j];

    #pragma unroll
    for (int i = 0; i < 8; i++) {
      float p[4], qq[4];
      #pragma unroll
      for (int d = 0; d < 4; d++) {
        float z = (acc[i][jj * 4 + d] - th[d]) * inv_tau;
        p[d] = 1.0f / (1.0f + __expf(-z));
        qq[d] = 1.0f - p[d];
      }
      // reduce leaf dim: bit d of leaf index selects p[d]
      float A[8];
      #pragma unroll
      for (int a = 0; a < 8; a++) A[a] = lf[2 * a] * qq[0] + lf[2 * a + 1] * p[0];
      float Bv[4];
      #pragma unroll
      for (int c = 0; c < 4; c++) Bv[c] = A[2 * c] * qq[1] + A[2 * c + 1] * p[1];
      float C0 = Bv[0] * qq[2] + Bv[1] * p[2];
      float C1 = Bv[2] * qq[2] + Bv[3] * p[2];
      float o = C0 * qq[3] + C1 * p[3];
      out[(size_t)(b0 + ty * 8 + i) * T_ + t] = o;
    }
  }
}

extern "C" void kernel_launch(void* const* d_in, const int* in_sizes, int n_in,
                              void* d_out, int out_size, void* d_ws, size_t ws_size,
                              hipStream_t stream) {
  const float* x    = (const float*)d_in[0];  // (B, F)
  const float* fl   = (const float*)d_in[1];  // (T, D, F)
  const float* thr  = (const float*)d_in[2];  // (T, D)
  const float* leaf = (const float*)d_in[3];  // (T, 16)
  float* out = (float*)d_out;                 // (B, T)
  float* w   = (float*)d_ws;                  // (T*D, F) softmax weights, 16 MB

  // kernel 1: softmax over F; 8192 rows, 4 rows/block
  softmax_rows<<<dim3((T_ * D_) / 4), dim3(256), 0, stream>>>(fl, w);

  // kernel 2: fused GEMM + epilogue
  dim3 grid(T_ / BT, B_ / BM);
  odst_fused<<<grid, dim3(256), 0, stream>>>(x, w, thr, leaf, out);
}

// Round 2
// 141.638 us; speedup vs baseline: 3.4086x; 3.4086x over previous
//
#include <hip/hip_runtime.h>
#include <stdint.h>

#define B_  4096
#define F_  512
#define T_  2048
#define D_  4
#define M_  (T_ * D_)   // 8192 = GEMM M (trees*dims)
#define TAU 0.2018004745467103f

typedef __attribute__((ext_vector_type(8))) short bf16x8;
typedef __attribute__((ext_vector_type(4))) float f32x4;

static __device__ __forceinline__ unsigned short f2bf(float f) {
  union { float f; uint32_t u; } v; v.f = f;
  uint32_t r = v.u + 0x7fffu + ((v.u >> 16) & 1u);  // RNE
  return (unsigned short)(r >> 16);
}

// ---------------------------------------------------------------------------
// x (B,F) fp32 -> bf16, 8 elems/thread
// ---------------------------------------------------------------------------
__global__ __launch_bounds__(256) void convert_x(const float* __restrict__ x,
                                                 unsigned short* __restrict__ xb) {
  size_t idx = (size_t)blockIdx.x * 256 + threadIdx.x;
  const float4* s = (const float4*)x + idx * 2;
  float4 a = s[0], b = s[1];
  bf16x8 o;
  o[0] = (short)f2bf(a.x); o[1] = (short)f2bf(a.y);
  o[2] = (short)f2bf(a.z); o[3] = (short)f2bf(a.w);
  o[4] = (short)f2bf(b.x); o[5] = (short)f2bf(b.y);
  o[6] = (short)f2bf(b.z); o[7] = (short)f2bf(b.w);
  *(bf16x8*)(xb + idx * 8) = o;
}

// ---------------------------------------------------------------------------
// softmax over F for each of the T*D rows, emit bf16. One wave per row.
// ---------------------------------------------------------------------------
__global__ __launch_bounds__(256) void softmax_bf16(
    const float* __restrict__ logits, unsigned short* __restrict__ wb) {
  int row  = blockIdx.x * 4 + (threadIdx.x >> 6);
  int lane = threadIdx.x & 63;
  const float* src = logits + (size_t)row * F_ + lane * 8;
  float4 v0 = *(const float4*)src;
  float4 v1 = *(const float4*)(src + 4);

  float mx = fmaxf(fmaxf(fmaxf(v0.x, v0.y), fmaxf(v0.z, v0.w)),
                   fmaxf(fmaxf(v1.x, v1.y), fmaxf(v1.z, v1.w)));
  #pragma unroll
  for (int m = 32; m >= 1; m >>= 1) mx = fmaxf(mx, __shfl_xor(mx, m, 64));

  float e[8];
  e[0] = __expf(v0.x - mx); e[1] = __expf(v0.y - mx);
  e[2] = __expf(v0.z - mx); e[3] = __expf(v0.w - mx);
  e[4] = __expf(v1.x - mx); e[5] = __expf(v1.y - mx);
  e[6] = __expf(v1.z - mx); e[7] = __expf(v1.w - mx);
  float s = e[0] + e[1] + e[2] + e[3] + e[4] + e[5] + e[6] + e[7];
  #pragma unroll
  for (int m = 32; m >= 1; m >>= 1) s += __shfl_xor(s, m, 64);
  float inv = 1.0f / s;

  bf16x8 o;
  #pragma unroll
  for (int i = 0; i < 8; i++) o[i] = (short)f2bf(e[i] * inv);
  *(bf16x8*)(wb + (size_t)row * F_ + lane * 8) = o;
}

// ---------------------------------------------------------------------------
// MFMA GEMM: C[M=8192][N=4096] = wb[M][F] * xb[N][F]^T, fused epilogue.
// 128x128 block tile, 4 waves in 2x2, each 64x64 (4x4 of 16x16x32 bf16 MFMA).
// C-layout puts the 4 tree-dims (m = t*4+d, d=reg) in one lane's acc regs ->
// epilogue is in-register. Output staged via padded LDS for coalesced stores.
// ---------------------------------------------------------------------------
__global__ __launch_bounds__(256) void odst_mfma(
    const unsigned short* __restrict__ wb,   // [M][F] bf16 (A operand)
    const unsigned short* __restrict__ xb,   // [B][F] bf16 (B operand)
    const float* __restrict__ thr,           // [T][4]
    const float* __restrict__ leaf,          // [T][16]
    float* __restrict__ out) {               // [B][T]
  __shared__ __align__(16) char smem[128 * 36 * 4];  // 18432 B
  unsigned short* As = (unsigned short*)smem;           // [128][32] bf16
  unsigned short* Bs = (unsigned short*)(smem + 8192);  // [128][32] bf16
  float* eb = (float*)smem;                             // [128][36] epilogue

  const int tid  = threadIdx.x;
  const int lane = tid & 63, wid = tid >> 6;
  const int wm = wid >> 1, wn = wid & 1;
  const int m0 = blockIdx.y * 128;
  const int n0 = blockIdx.x * 128;
  const int col = lane & 15, quad = lane >> 4;

  f32x4 acc[4][4] = {};

  for (int k0 = 0; k0 < F_; k0 += 32) {
    __syncthreads();
    #pragma unroll
    for (int c = 0; c < 2; c++) {
      int f = wid * 128 + c * 64 + lane;   // 0..511: 16B chunk id
      int row = f >> 2, chunk = f & 3;
      const unsigned short* ga = wb + (size_t)(m0 + row) * F_ + k0 + chunk * 8;
      const unsigned short* gb = xb + (size_t)(n0 + row) * F_ + k0 + chunk * 8;
      // LDS dst: wave-uniform base + lane*16 (natural [row][k] order)
      __builtin_amdgcn_global_load_lds(
          (const __attribute__((address_space(1))) uint32_t*)ga,
          (__attribute__((address_space(3))) uint32_t*)(As + (size_t)(wid * 128 + c * 64) * 8),
          16, 0, 0);
      __builtin_amdgcn_global_load_lds(
          (const __attribute__((address_space(1))) uint32_t*)gb,
          (__attribute__((address_space(3))) uint32_t*)(Bs + (size_t)(wid * 128 + c * 64) * 8),
          16, 0, 0);
    }
    __syncthreads();  // compiler drains vmcnt before barrier

    bf16x8 a[4], b[4];
    #pragma unroll
    for (int i = 0; i < 4; i++)
      a[i] = *(const bf16x8*)(As + ((wm * 64 + i * 16 + col) << 5) + (quad << 3));
    #pragma unroll
    for (int j = 0; j < 4; j++)
      b[j] = *(const bf16x8*)(Bs + ((wn * 64 + j * 16 + col) << 5) + (quad << 3));
    #pragma unroll
    for (int i = 0; i < 4; i++)
      #pragma unroll
      for (int j = 0; j < 4; j++)
        acc[i][j] = __builtin_amdgcn_mfma_f32_16x16x32_bf16(a[i], b[j], acc[i][j], 0, 0, 0);
  }

  __syncthreads();  // all frag reads done; reuse LDS for epilogue

  const float inv_tau = 1.0f / TAU;
  #pragma unroll
  for (int i = 0; i < 4; i++) {
    int t = (m0 >> 2) + wm * 16 + i * 4 + quad;       // global tree
    float4 th  = *(const float4*)(thr + t * 4);
    float4 lf0 = *(const float4*)(leaf + t * 16);
    float4 lf1 = *(const float4*)(leaf + t * 16 + 4);
    float4 lf2 = *(const float4*)(leaf + t * 16 + 8);
    float4 lf3 = *(const float4*)(leaf + t * 16 + 12);
    // exp(-z) = exp(a*c1 + c2), c1 = -1/tau, c2 = th/tau
    float c2x = th.x * inv_tau, c2y = th.y * inv_tau,
          c2z = th.z * inv_tau, c2w = th.w * inv_tau;
    #pragma unroll
    for (int j = 0; j < 4; j++) {
      float p0 = __builtin_amdgcn_rcpf(1.0f + __expf(fmaf(acc[i][j][0], -inv_tau, c2x)));
      float p1 = __builtin_amdgcn_rcpf(1.0f + __expf(fmaf(acc[i][j][1], -inv_tau, c2y)));
      float p2 = __builtin_amdgcn_rcpf(1.0f + __expf(fmaf(acc[i][j][2], -inv_tau, c2z)));
      float p3 = __builtin_amdgcn_rcpf(1.0f + __expf(fmaf(acc[i][j][3], -inv_tau, c2w)));
      float q0 = 1.0f - p0, q1 = 1.0f - p1, q2 = 1.0f - p2, q3 = 1.0f - p3;
      // leaf bit d (weight 2^d) selects p_d
      float A0 = lf0.x * q0 + lf0.y * p0;
      float A1 = lf0.z * q0 + lf0.w * p0;
      float A2 = lf1.x * q0 + lf1.y * p0;
      float A3 = lf1.z * q0 + lf1.w * p0;
      float A4 = lf2.x * q0 + lf2.y * p0;
      float A5 = lf2.z * q0 + lf2.w * p0;
      float A6 = lf3.x * q0 + lf3.y * p0;
      float A7 = lf3.z * q0 + lf3.w * p0;
      float B0 = A0 * q1 + A1 * p1;
      float B1 = A2 * q1 + A3 * p1;
      float B2 = A4 * q1 + A5 * p1;
      float B3 = A6 * q1 + A7 * p1;
      float C0 = B0 * q2 + B1 * p2;
      float C1 = B2 * q2 + B3 * p2;
      float o  = C0 * q3 + C1 * p3;
      int bl = wn * 64 + j * 16 + col;                 // batch within block
      int tl = wm * 16 + i * 4 + quad;                 // tree within block
      eb[bl * 36 + tl] = o;
    }
  }
  __syncthreads();

  // cooperative coalesced store: 128 batch rows x 32 trees
  #pragma unroll
  for (int q = 0; q < 4; q++) {
    int row = q * 32 + (tid >> 3);
    int seg = tid & 7;
    float4 v = *(const float4*)(eb + row * 36 + seg * 4);
    *(float4*)(out + (size_t)(n0 + row) * T_ + (m0 >> 2) + seg * 4) = v;
  }
}

extern "C" void kernel_launch(void* const* d_in, const int* in_sizes, int n_in,
                              void* d_out, int out_size, void* d_ws, size_t ws_size,
                              hipStream_t stream) {
  const float* x    = (const float*)d_in[0];  // (B, F)
  const float* fl   = (const float*)d_in[1];  // (T, D, F)
  const float* thr  = (const float*)d_in[2];  // (T, D)
  const float* leaf = (const float*)d_in[3];  // (T, 16)
  float* out = (float*)d_out;                 // (B, T)

  unsigned short* wb = (unsigned short*)d_ws;                    // 8 MB bf16 [M][F]
  unsigned short* xb = (unsigned short*)((char*)d_ws + (size_t)M_ * F_ * 2);  // 4 MB

  convert_x<<<dim3((B_ * F_) / (256 * 8)), dim3(256), 0, stream>>>(x, xb);
  softmax_bf16<<<dim3(M_ / 4), dim3(256), 0, stream>>>(fl, wb);
  odst_mfma<<<dim3(B_ / 128, M_ / 128), dim3(256), 0, stream>>>(wb, xb, thr, leaf, out);
}

// Round 3
// 132.455 us; speedup vs baseline: 3.6449x; 1.0693x over previous
//
#include <hip/hip_runtime.h>
#include <stdint.h>

#define B_  4096
#define F_  512
#define T_  2048
#define D_  4
#define M_  (T_ * D_)   // 8192 = GEMM M (trees*dims)
#define TAU 0.2018004745467103f

#define BM 128   // m tile (trees*4)
#define BN 256   // n tile (batch)
#define BK 64    // k tile

typedef __attribute__((ext_vector_type(8)))  short bf16x8;
typedef __attribute__((ext_vector_type(16))) float f32x16;

static __device__ __forceinline__ unsigned short f2bf(float f) {
  union { float f; uint32_t u; } v; v.f = f;
  uint32_t r = v.u + 0x7fffu + ((v.u >> 16) & 1u);  // RNE
  return (unsigned short)(r >> 16);
}

// ---------------------------------------------------------------------------
// x (B,F) fp32 -> bf16, 8 elems/thread
// ---------------------------------------------------------------------------
__global__ __launch_bounds__(256) void convert_x(const float* __restrict__ x,
                                                 unsigned short* __restrict__ xb) {
  size_t idx = (size_t)blockIdx.x * 256 + threadIdx.x;
  const float4* s = (const float4*)x + idx * 2;
  float4 a = s[0], b = s[1];
  bf16x8 o;
  o[0] = (short)f2bf(a.x); o[1] = (short)f2bf(a.y);
  o[2] = (short)f2bf(a.z); o[3] = (short)f2bf(a.w);
  o[4] = (short)f2bf(b.x); o[5] = (short)f2bf(b.y);
  o[6] = (short)f2bf(b.z); o[7] = (short)f2bf(b.w);
  *(bf16x8*)(xb + idx * 8) = o;
}

// ---------------------------------------------------------------------------
// softmax over F for each of the T*D rows, emit bf16. One wave per row.
// ---------------------------------------------------------------------------
__global__ __launch_bounds__(256) void softmax_bf16(
    const float* __restrict__ logits, unsigned short* __restrict__ wb) {
  int row  = blockIdx.x * 4 + (threadIdx.x >> 6);
  int lane = threadIdx.x & 63;
  const float* src = logits + (size_t)row * F_ + lane * 8;
  float4 v0 = *(const float4*)src;
  float4 v1 = *(const float4*)(src + 4);

  float mx = fmaxf(fmaxf(fmaxf(v0.x, v0.y), fmaxf(v0.z, v0.w)),
                   fmaxf(fmaxf(v1.x, v1.y), fmaxf(v1.z, v1.w)));
  #pragma unroll
  for (int m = 32; m >= 1; m >>= 1) mx = fmaxf(mx, __shfl_xor(mx, m, 64));

  float e[8];
  e[0] = __expf(v0.x - mx); e[1] = __expf(v0.y - mx);
  e[2] = __expf(v0.z - mx); e[3] = __expf(v0.w - mx);
  e[4] = __expf(v1.x - mx); e[5] = __expf(v1.y - mx);
  e[6] = __expf(v1.z - mx); e[7] = __expf(v1.w - mx);
  float s = e[0] + e[1] + e[2] + e[3] + e[4] + e[5] + e[6] + e[7];
  #pragma unroll
  for (int m = 32; m >= 1; m >>= 1) s += __shfl_xor(s, m, 64);
  float inv = 1.0f / s;

  bf16x8 o;
  #pragma unroll
  for (int i = 0; i < 8; i++) o[i] = (short)f2bf(e[i] * inv);
  *(bf16x8*)(wb + (size_t)row * F_ + lane * 8) = o;
}

// ---------------------------------------------------------------------------
// MFMA GEMM: C[M][N] = wb[M][F] * xb[N][F]^T + fused sigmoid/leaf epilogue.
// 128x256 block tile, BK=64. 4 waves in 2(m)x2(n); wave tile 64x128 =
// 2x4 of v_mfma_f32_32x32x16_bf16.
// LDS staging via global_load_lds(16B) with XOR chunk swizzle
// (c' = c ^ (row&7)) so b128 frag reads are bank-conflict-free.
// C-layout per lane: n=lane&31, d=reg&3, tree_local=2*(reg>>2)+(lane>>5).
// ---------------------------------------------------------------------------
__global__ __launch_bounds__(256, 2) void odst_mfma(
    const unsigned short* __restrict__ wb,   // [M][F] bf16 (A)
    const unsigned short* __restrict__ xb,   // [B][F] bf16 (B)
    const float* __restrict__ thr,           // [T][4]
    const float* __restrict__ leaf,          // [T][16]
    float* __restrict__ out) {               // [B][T]
  __shared__ __align__(16) char smem[49152];
  unsigned short* As = (unsigned short*)smem;            // [128][64] swizzled, 16KB
  unsigned short* Bs = (unsigned short*)(smem + 16384);  // [256][64] swizzled, 32KB
  float* eb = (float*)smem;                              // [256][34] epilogue

  const int tid  = threadIdx.x;
  const int lane = tid & 63, wid = tid >> 6;
  const int wm = wid >> 1, wn = wid & 1;
  const int m0 = blockIdx.y * BM;
  const int n0 = blockIdx.x * BN;
  const int col = lane & 31, hi = lane >> 5;
  const int c7  = col & 7;

  // per-lane global staging pointers (k0=0); advance by BK per iter
  const unsigned short* a_src[4];
  #pragma unroll
  for (int q = 0; q < 4; q++) {
    int s = wid * 64 + q * 256 + lane;       // slot 0..1023
    int r = s >> 3, cp = s & 7, c = cp ^ (r & 7);
    a_src[q] = wb + (size_t)(m0 + r) * F_ + c * 8;
  }
  const unsigned short* b_src[8];
  #pragma unroll
  for (int q = 0; q < 8; q++) {
    int s = wid * 64 + q * 256 + lane;       // slot 0..2047
    int r = s >> 3, cp = s & 7, c = cp ^ (r & 7);
    b_src[q] = xb + (size_t)(n0 + r) * F_ + c * 8;
  }
  // frag read bases (bytes into As/Bs), row*128
  int a_base[2], b_base[4];
  #pragma unroll
  for (int i = 0; i < 2; i++) a_base[i] = (wm * 64 + i * 32 + col) << 7;
  #pragma unroll
  for (int j = 0; j < 4; j++) b_base[j] = (wn * 128 + j * 32 + col) << 7;

  f32x16 acc[2][4] = {};

  for (int k0 = 0; k0 < F_; k0 += BK) {
    __syncthreads();
    #pragma unroll
    for (int q = 0; q < 4; q++)
      __builtin_amdgcn_global_load_lds(
          (const __attribute__((address_space(1))) uint32_t*)(a_src[q] + k0),
          (__attribute__((address_space(3))) uint32_t*)(As + (wid * 64 + q * 256) * 8),
          16, 0, 0);
    #pragma unroll
    for (int q = 0; q < 8; q++)
      __builtin_amdgcn_global_load_lds(
          (const __attribute__((address_space(1))) uint32_t*)(b_src[q] + k0),
          (__attribute__((address_space(3))) uint32_t*)(Bs + (wid * 64 + q * 256) * 8),
          16, 0, 0);
    __syncthreads();

    #pragma unroll
    for (int ks = 0; ks < 4; ks++) {
      int cp = ((ks * 2 + hi) ^ c7) << 4;    // physical chunk byte offset
      bf16x8 a[2], b[4];
      #pragma unroll
      for (int i = 0; i < 2; i++)
        a[i] = *(const bf16x8*)((char*)As + a_base[i] + cp);
      #pragma unroll
      for (int j = 0; j < 4; j++)
        b[j] = *(const bf16x8*)((char*)Bs + b_base[j] + cp);
      #pragma unroll
      for (int i = 0; i < 2; i++)
        #pragma unroll
        for (int j = 0; j < 4; j++)
          acc[i][j] = __builtin_amdgcn_mfma_f32_32x32x16_bf16(a[i], b[j], acc[i][j], 0, 0, 0);
    }
  }

  __syncthreads();  // frag reads done; reuse LDS for epilogue

  const float inv_tau = 1.0f / TAU;
  const int t0 = m0 >> 2;
  #pragma unroll
  for (int i = 0; i < 2; i++) {
    #pragma unroll
    for (int g = 0; g < 4; g++) {
      int tl = wm * 16 + i * 8 + 2 * g + hi;          // tree within block [0,32)
      int t  = t0 + tl;
      float4 th  = *(const float4*)(thr + t * 4);
      float4 lf0 = *(const float4*)(leaf + t * 16);
      float4 lf1 = *(const float4*)(leaf + t * 16 + 4);
      float4 lf2 = *(const float4*)(leaf + t * 16 + 8);
      float4 lf3 = *(const float4*)(leaf + t * 16 + 12);
      float c2x = th.x * inv_tau, c2y = th.y * inv_tau,
            c2z = th.z * inv_tau, c2w = th.w * inv_tau;
      #pragma unroll
      for (int j = 0; j < 4; j++) {
        float p0 = __builtin_amdgcn_rcpf(1.0f + __expf(fmaf(acc[i][j][g * 4 + 0], -inv_tau, c2x)));
        float p1 = __builtin_amdgcn_rcpf(1.0f + __expf(fmaf(acc[i][j][g * 4 + 1], -inv_tau, c2y)));
        float p2 = __builtin_amdgcn_rcpf(1.0f + __expf(fmaf(acc[i][j][g * 4 + 2], -inv_tau, c2z)));
        float p3 = __builtin_amdgcn_rcpf(1.0f + __expf(fmaf(acc[i][j][g * 4 + 3], -inv_tau, c2w)));
        float q0 = 1.0f - p0, q1 = 1.0f - p1, q2 = 1.0f - p2, q3 = 1.0f - p3;
        float A0 = lf0.x * q0 + lf0.y * p0;
        float A1 = lf0.z * q0 + lf0.w * p0;
        float A2 = lf1.x * q0 + lf1.y * p0;
        float A3 = lf1.z * q0 + lf1.w * p0;
        float A4 = lf2.x * q0 + lf2.y * p0;
        float A5 = lf2.z * q0 + lf2.w * p0;
        float A6 = lf3.x * q0 + lf3.y * p0;
        float A7 = lf3.z * q0 + lf3.w * p0;
        float B0 = A0 * q1 + A1 * p1;
        float B1 = A2 * q1 + A3 * p1;
        float B2 = A4 * q1 + A5 * p1;
        float B3 = A6 * q1 + A7 * p1;
        float C0 = B0 * q2 + B1 * p2;
        float C1 = B2 * q2 + B3 * p2;
        float o  = C0 * q3 + C1 * p3;
        int bl = wn * 128 + j * 32 + col;              // batch within block
        eb[bl * 34 + tl] = o;                          // stride 34: 2-way (free)
      }
    }
  }
  __syncthreads();

  // coalesced store: 256 batch rows x 32 trees, float2 per thread-slot
  #pragma unroll
  for (int q = 0; q < 16; q++) {
    int row = q * 16 + (tid >> 4);
    int s   = tid & 15;
    float2 v = *(const float2*)(eb + row * 34 + s * 2);
    *(float2*)(out + (size_t)(n0 + row) * T_ + t0 + s * 2) = v;
  }
}

extern "C" void kernel_launch(void* const* d_in, const int* in_sizes, int n_in,
                              void* d_out, int out_size, void* d_ws, size_t ws_size,
                              hipStream_t stream) {
  const float* x    = (const float*)d_in[0];  // (B, F)
  const float* fl   = (const float*)d_in[1];  // (T, D, F)
  const float* thr  = (const float*)d_in[2];  // (T, D)
  const float* leaf = (const float*)d_in[3];  // (T, 16)
  float* out = (float*)d_out;                 // (B, T)

  unsigned short* wb = (unsigned short*)d_ws;                               // 8 MB
  unsigned short* xb = (unsigned short*)((char*)d_ws + (size_t)M_ * F_ * 2);// 4 MB

  convert_x<<<dim3((B_ * F_) / (256 * 8)), dim3(256), 0, stream>>>(x, xb);
  softmax_bf16<<<dim3(M_ / 4), dim3(256), 0, stream>>>(fl, wb);
  odst_mfma<<<dim3(B_ / BN, M_ / BM), dim3(256), 0, stream>>>(wb, xb, thr, leaf, out);
}